// Round 1
// baseline (1474.044 us; speedup 1.0000x reference)
//
#include <hip/hip_runtime.h>
#include <cstdint>

#define TT  1024
#define BB  32
#define HH  8
#define DD  32
#define YDN 97
#define INN 256
#define BH  (BB*HH)

typedef float v2f __attribute__((ext_vector_type(2)));
typedef float v4f __attribute__((ext_vector_type(4)));

// packed fp32 FMA (v_pk_fma_f32 on CDNA)
#define PK(acc, a, b) (acc) = __builtin_elementwise_fma((a), (b), (acc))

template<int C>
__device__ __forceinline__ float dppf(float x) {
    return __int_as_float(__builtin_amdgcn_update_dpp(
        0, __float_as_int(x), C, 0xF, 0xF, true));
}
__device__ __forceinline__ float swz16(float x) {
    return __int_as_float(__builtin_amdgcn_ds_swizzle(__float_as_int(x), 0x401F));
}
__device__ __forceinline__ float red_max32(float v) {
    v = fmaxf(v, dppf<0xB1>(v));
    v = fmaxf(v, dppf<0x4E>(v));
    v = fmaxf(v, dppf<0x141>(v));
    v = fmaxf(v, dppf<0x140>(v));
    v = fmaxf(v, swz16(v));
    return v;
}
__device__ __forceinline__ float red_sum32(float v) {
    v += dppf<0xB1>(v);
    v += dppf<0x4E>(v);
    v += dppf<0x141>(v);
    v += dppf<0x140>(v);
    v += swz16(v);
    return v;
}
__device__ __forceinline__ float rdlane(float v, int l) {
    return __int_as_float(__builtin_amdgcn_readlane(__float_as_int(v), l));
}

// exp with overflow guard (values are O(1); clamp never binds in practice)
__device__ __forceinline__ float cexp(float v) {
    return __expf(fminf(v, 60.f));
}

// 32-length dot: x,w are 16 v2f register arrays
__device__ __forceinline__ float dot32(const v2f* x, const v2f* w) {
    v2f a0 = {0.f, 0.f}, a1 = {0.f, 0.f};
    #pragma unroll
    for (int g = 0; g < 8; g++) {
        PK(a0, x[2*g],   w[2*g]);
        PK(a1, x[2*g+1], w[2*g+1]);
    }
    v2f s = a0 + a1;
    return s.x + s.y;
}

// ---------------------------------------------------------------------------
// Kernel 1: x = softmax(h) over last dim (rows of 32)
// ---------------------------------------------------------------------------
__global__ __launch_bounds__(256, 1) void softmax_x_kernel(
    const float* __restrict__ hg, float* __restrict__ xg)
{
    const int row  = blockIdx.x * 8 + (threadIdx.x >> 5);
    const int lane = threadIdx.x & 31;
    float v = hg[(size_t)row * DD + lane];
    float m = red_max32(v);
    float ex = __expf(v - m);
    float sm = red_sum32(ex);
    xg[(size_t)row * DD + lane] = ex * __builtin_amdgcn_rcpf(sm);
}

// ---------------------------------------------------------------------------
// Kernel 2: recurrent SRWM + fast-weight memory.
// ONE WAVE per (b,h): all state in registers, zero barriers.
// Lane roles (64 lanes):
//   S0: Wy col = lane            (cols 0..63)   16 v2f each
//   S1: lane<=32: Wy col 64+lane (cols 64..96); lanes 33..36: wb col lane-33
//   S2: lane<32: Wq col lane; lane>=32: Wk col lane-32
//   F : split rows: lane<32: F[0:16, lane]; lane>=32: F[16:32, lane-32] (8 v2f)
// Cross-lane broadcast of exp(q/k) and exp(fq/fk) via same-wave LDS
// (lgkmcnt only, no s_barrier). F-phase(t-1) overlaps the qk LDS round-trip
// of step t. beta/fb broadcast via v_readlane.
// ---------------------------------------------------------------------------

#define F_PHASE(TP, PB)                                                       \
    {                                                                         \
        const v4f* fsp4 = (const v4f*)f_s[PB];                                \
        v2f fqh[8], fkh[8];                                                   \
        _Pragma("unroll")                                                     \
        for (int j = 0; j < 4; j++) {                                         \
            v4f a = fsp4[4*half + j];                                         \
            fqh[2*j] = a.xy; fqh[2*j+1] = a.zw;                               \
        }                                                                     \
        _Pragma("unroll")                                                     \
        for (int j = 0; j < 4; j++) {                                         \
            v4f a = fsp4[8 + 4*half + j];                                     \
            fkh[2*j] = a.xy; fkh[2*j+1] = a.zw;                               \
        }                                                                     \
        v2f a0 = {0.f,0.f}, a1 = {0.f,0.f};                                   \
        _Pragma("unroll")                                                     \
        for (int j = 0; j < 4; j++) {                                         \
            PK(a0, fkh[2*j],   f3[2*j]);                                      \
            PK(a1, fkh[2*j+1], f3[2*j+1]);                                    \
        }                                                                     \
        v2f vt = a0 + a1;                                                     \
        float vh = vt.x + vt.y;                                               \
        float vold = vh + __shfl_xor(vh, 32, 64);                             \
        float ofv = __shfl_xor(fv_p, 32, 64);                                 \
        float fvv = half ? ofv : fv_p;                                        \
        float dlt = fb_p * (fvv - vold * rrfk_p) * rrfk_p;                    \
        v2f d2 = {dlt, dlt};                                                  \
        v2f o0 = {0.f,0.f}, o1 = {0.f,0.f};                                   \
        _Pragma("unroll")                                                     \
        for (int j = 0; j < 4; j++) {                                         \
            PK(f3[2*j],   d2, fkh[2*j]);                                      \
            PK(o0, fqh[2*j],   f3[2*j]);                                      \
            PK(f3[2*j+1], d2, fkh[2*j+1]);                                    \
            PK(o1, fqh[2*j+1], f3[2*j+1]);                                    \
        }                                                                     \
        v2f ot = o0 + o1;                                                     \
        float oh = ot.x + ot.y;                                               \
        float oo = (oh + __shfl_xor(oh, 32, 64)) * rrfq_p;                    \
        if (half == 0)                                                        \
            Og[((size_t)(TP) * BH + bh) * DD + lane] = oo;                    \
    }

#define STEP(T, XC, BUF, PF, FP)                                              \
    {                                                                         \
        /* dots with x (uses state BEFORE this step's update) */              \
        float p0 = dot32(XC, s0);  /* y[lane]            */                   \
        float p1 = dot32(XC, s1);  /* y[64+lane] / wb pre */                  \
        float p2 = dot32(XC, s2);  /* qhat / khat pre     */                  \
        float exqk = cexp(p2);                                                \
        float exf  = cexp(p0);                                                \
        float sig  = __builtin_amdgcn_rcpf(1.f + __expf(-p1));                \
        qk_s[lane]     = exqk;                                                \
        f_s[BUF][lane] = exf;                                                 \
        if (PF) { /* prefetch x(T+2) into XC (distance-2 double buffer) */    \
            const v4f* p = (const v4f*)(xg + ((size_t)((T)+2)*BH + bh)*DD);   \
            _Pragma("unroll")                                                 \
            for (int g = 0; g < 8; g++) {                                     \
                v4f v = p[g];                                                 \
                XC[2*g] = v.xy; XC[2*g+1] = v.zw;                             \
            }                                                                 \
        }                                                                     \
        if (FP) { F_PHASE((T)-1, (BUF)^1) }  /* hides qk write->read */       \
        float sqk = red_sum32(exqk);                                          \
        float oqk = __shfl_xor(sqk, 32, 64);                                  \
        float rrq = __builtin_amdgcn_rcpf(half ? oqk : sqk);                  \
        float rrk = __builtin_amdgcn_rcpf(half ? sqk : oqk);                  \
        float b0  = rdlane(sig, 33), b1v = rdlane(sig, 34);                   \
        float b2v = rdlane(sig, 35), b3v = rdlane(sig, 36);                   \
        asm volatile("s_waitcnt lgkmcnt(0)" ::: "memory");                    \
        v2f U[16], Kr[16];                                                    \
        {                                                                     \
            const v4f* qs4 = (const v4f*)qk_s;                                \
            v2f rrq2 = {rrq, rrq}, nrk2 = {-rrk, -rrk};                       \
            _Pragma("unroll")                                                 \
            for (int j = 0; j < 8; j++) {                                     \
                v4f qv = qs4[j], kv = qs4[8 + j];                             \
                v2f k0 = kv.xy, k1 = kv.zw;                                   \
                Kr[2*j] = k0; Kr[2*j+1] = k1;                                 \
                v2f u0 = qv.xy * rrq2; PK(u0, nrk2, k0); U[2*j]   = u0;       \
                v2f u1 = qv.zw * rrq2; PK(u1, nrk2, k1); U[2*j+1] = u1;       \
            }                                                                 \
        }                                                                     \
        { /* W[d,e] += beta * (u . W[:,e]) * rrk * khat_d  for S0,S1,S2 */    \
            float du = dot32(U, s0);                                          \
            float bs = b0 * rrk * du;                                         \
            v2f bs2 = {bs, bs};                                               \
            _Pragma("unroll")                                                 \
            for (int j = 0; j < 16; j++) PK(s0[j], bs2, Kr[j]);               \
        }                                                                     \
        {                                                                     \
            float du = dot32(U, s1);                                          \
            float bsel = (lane <= 32) ? b0 : b3v;                             \
            float bs = bsel * rrk * du;                                       \
            v2f bs2 = {bs, bs};                                               \
            _Pragma("unroll")                                                 \
            for (int j = 0; j < 16; j++) PK(s1[j], bs2, Kr[j]);               \
        }                                                                     \
        {                                                                     \
            float du = dot32(U, s2);                                          \
            float bsel = half ? b2v : b1v;                                    \
            float bs = bsel * rrk * du;                                       \
            v2f bs2 = {bs, bs};                                               \
            _Pragma("unroll")                                                 \
            for (int j = 0; j < 16; j++) PK(s2[j], bs2, Kr[j]);               \
        }                                                                     \
        /* save fast-weight inputs for F_PHASE(T) next step */                \
        float sf  = red_sum32(exf);                                           \
        float ofs = __shfl_xor(sf, 32, 64);                                   \
        rrfq_p = __builtin_amdgcn_rcpf(half ? ofs : sf);                      \
        rrfk_p = __builtin_amdgcn_rcpf(half ? sf : ofs);                      \
        fv_p = p1;                                                            \
        fb_p = rdlane(sig, 32);                                               \
    }

__global__ __launch_bounds__(64, 1) void srwm_fwm_kernel(
    const float* __restrict__ xg,
    const float* __restrict__ Wy_g, const float* __restrict__ Wq_g,
    const float* __restrict__ Wk_g, const float* __restrict__ wb_g,
    const float* __restrict__ sWy_g, const float* __restrict__ sWq_g,
    const float* __restrict__ sWk_g, const float* __restrict__ swb_g,
    const float* __restrict__ F_g,
    float* __restrict__ Og)
{
    const int bh   = blockIdx.x;
    const int hh   = bh & 7;
    const int lane = threadIdx.x;   // 0..63
    const int half = lane >> 5;
    const int l32  = lane & 31;

    __shared__ __align__(16) float qk_s[64];
    __shared__ __align__(16) float f_s[2][64];

    v2f s0[16], s1[16], s2[16], f3[8];
    v2f XA[16], XB[16];

    // ---- init S0: Wy col = lane ----
    {
        const float* wp = Wy_g  + (size_t)hh * DD * YDN + lane;
        const float* sp = sWy_g + (size_t)bh * DD * YDN + lane;
        #pragma unroll
        for (int d = 0; d < 16; d++) {
            v2f t;
            t.x = wp[(2*d)   * YDN] + sp[(2*d)   * YDN];
            t.y = wp[(2*d+1) * YDN] + sp[(2*d+1) * YDN];
            s0[d] = t;
        }
    }
    // ---- init S1: Wy cols 64..96 (lanes 0..32) + wb (lanes 33..36) ----
    {
        const float* wp = nullptr; const float* sp = nullptr; int str = 0;
        if (lane <= 32) {
            wp = Wy_g  + (size_t)hh * DD * YDN + 64 + lane;
            sp = sWy_g + (size_t)bh * DD * YDN + 64 + lane;  str = YDN;
        } else if (lane <= 36) {
            wp = wb_g  + (size_t)hh * DD * 4 + (lane - 33);
            sp = swb_g + (size_t)bh * DD * 4 + (lane - 33);  str = 4;
        }
        #pragma unroll
        for (int d = 0; d < 16; d++) {
            v2f t = {0.f, 0.f};
            if (wp) {
                t.x = wp[(2*d)   * str] + sp[(2*d)   * str];
                t.y = wp[(2*d+1) * str] + sp[(2*d+1) * str];
            }
            s1[d] = t;
        }
    }
    // ---- init S2: Wq col l32 (half 0) / Wk col l32 (half 1) ----
    {
        const float* wp = (half == 0) ? (Wq_g  + (size_t)hh * DD * DD + l32)
                                      : (Wk_g  + (size_t)hh * DD * DD + l32);
        const float* sp = (half == 0) ? (sWq_g + (size_t)bh * DD * DD + l32)
                                      : (sWk_g + (size_t)bh * DD * DD + l32);
        #pragma unroll
        for (int d = 0; d < 16; d++) {
            v2f t;
            t.x = wp[(2*d)   * DD] + sp[(2*d)   * DD];
            t.y = wp[(2*d+1) * DD] + sp[(2*d+1) * DD];
            s2[d] = t;
        }
    }
    // ---- init F: rows 16*half .. 16*half+15 of col l32 ----
    {
        const float* fp = F_g + (size_t)bh * DD * DD + (size_t)(16*half) * DD + l32;
        #pragma unroll
        for (int j = 0; j < 8; j++) {
            v2f t;
            t.x = fp[(2*j)   * DD];
            t.y = fp[(2*j+1) * DD];
            f3[j] = t;
        }
    }
    // ---- x(0), x(1) ----
    {
        const v4f* p0 = (const v4f*)(xg + (size_t)bh * DD);
        const v4f* p1 = (const v4f*)(xg + ((size_t)BH + bh) * DD);
        #pragma unroll
        for (int g = 0; g < 8; g++) {
            v4f a = p0[g], b = p1[g];
            XA[2*g] = a.xy; XA[2*g+1] = a.zw;
            XB[2*g] = b.xy; XB[2*g+1] = b.zw;
        }
    }

    float fv_p = 0.f, fb_p = 0.f, rrfq_p = 0.f, rrfk_p = 0.f;

    STEP(0, XA, 0, 1, 0)
    for (int t = 1; t < TT - 3; t += 2) {
        STEP(t,     XB, 1, 1, 1)
        STEP(t + 1, XA, 0, 1, 1)
    }
    STEP(TT - 3, XB, 1, 1, 1)   // t=1021, prefetches x(1023) -> XB
    STEP(TT - 2, XA, 0, 0, 1)   // t=1022
    STEP(TT - 1, XB, 1, 0, 1)   // t=1023
    F_PHASE(TT - 1, 1)          // drain
}

// ---------------------------------------------------------------------------
// Kernel 3: out = h + O @ W_out^T   (M=32768, N=K=256), fp32.
// ---------------------------------------------------------------------------
#define GM 128
#define GN 64
#define GK 16

__global__ __launch_bounds__(256, 1) void out_proj_kernel(
    const float* __restrict__ O, const float* __restrict__ W,
    const float* __restrict__ hg, float* __restrict__ outg)
{
    __shared__ float As[GK][GM + 4];
    __shared__ float Bs[GK][GN + 4];
    const int tid = threadIdx.x;
    const int tx  = tid & 15;
    const int ty  = tid >> 4;
    const int r0  = blockIdx.x * GM;
    const int c0  = blockIdx.y * GN;

    float acc[8][4];
    #pragma unroll
    for (int i = 0; i < 8; i++)
        #pragma unroll
        for (int j = 0; j < 4; j++) acc[i][j] = 0.f;

    const int am  = tid >> 1;
    const int akg = (tid & 1) * 8;
    const int bn  = tid >> 2;
    const int bkg = (tid & 3) * 4;

    for (int k0 = 0; k0 < INN; k0 += GK) {
        float4 a0 = *(const float4*)(O + (size_t)(r0 + am) * INN + k0 + akg);
        float4 a1 = *(const float4*)(O + (size_t)(r0 + am) * INN + k0 + akg + 4);
        float4 w0 = *(const float4*)(W + (size_t)(c0 + bn) * INN + k0 + bkg);
        As[akg+0][am] = a0.x; As[akg+1][am] = a0.y; As[akg+2][am] = a0.z; As[akg+3][am] = a0.w;
        As[akg+4][am] = a1.x; As[akg+5][am] = a1.y; As[akg+6][am] = a1.z; As[akg+7][am] = a1.w;
        Bs[bkg+0][bn] = w0.x; Bs[bkg+1][bn] = w0.y;
        Bs[bkg+2][bn] = w0.z; Bs[bkg+3][bn] = w0.w;
        __syncthreads();
        #pragma unroll
        for (int k = 0; k < GK; k++) {
            float4 av0 = *(const float4*)&As[k][ty * 8];
            float4 av1 = *(const float4*)&As[k][ty * 8 + 4];
            float4 bv  = *(const float4*)&Bs[k][tx * 4];
            float a[8] = {av0.x, av0.y, av0.z, av0.w, av1.x, av1.y, av1.z, av1.w};
            float bb[4] = {bv.x, bv.y, bv.z, bv.w};
            #pragma unroll
            for (int i = 0; i < 8; i++)
                #pragma unroll
                for (int j = 0; j < 4; j++) acc[i][j] += a[i] * bb[j];
        }
        __syncthreads();
    }

    #pragma unroll
    for (int i = 0; i < 8; i++) {
        size_t r = (size_t)(r0 + ty * 8 + i);
        float4 hv = *(const float4*)(hg + r * INN + c0 + tx * 4);
        float4 o;
        o.x = hv.x + acc[i][0];
        o.y = hv.y + acc[i][1];
        o.z = hv.z + acc[i][2];
        o.w = hv.w + acc[i][3];
        *(float4*)(outg + r * INN + c0 + tx * 4) = o;
    }
}

// ---------------------------------------------------------------------------
extern "C" void kernel_launch(void* const* d_in, const int* in_sizes, int n_in,
                              void* d_out, int out_size, void* d_ws, size_t ws_size,
                              hipStream_t stream)
{
    (void)in_sizes; (void)n_in; (void)out_size; (void)ws_size;

    const float* hg   = (const float*)d_in[0];
    const float* Wy   = (const float*)d_in[1];
    const float* Wq   = (const float*)d_in[2];
    const float* Wk   = (const float*)d_in[3];
    const float* wb   = (const float*)d_in[4];
    const float* Wout = (const float*)d_in[5];
    const float* sWy  = (const float*)d_in[6];
    const float* sWq  = (const float*)d_in[7];
    const float* sWk  = (const float*)d_in[8];
    const float* swb  = (const float*)d_in[9];
    const float* Fw   = (const float*)d_in[10];
    float* out = (float*)d_out;

    float* xg = (float*)d_ws;                      // (T,B,H,D) fp32
    float* Og = xg + (size_t)TT * BB * INN;        // (T,B,IN)  fp32

    softmax_x_kernel<<<TT * BB * HH / 8, 256, 0, stream>>>(hg, xg);
    srwm_fwm_kernel<<<BB * HH, 64, 0, stream>>>(xg, Wy, Wq, Wk, wb,
                                                sWy, sWq, sWk, swb, Fw, Og);
    out_proj_kernel<<<dim3(TT * BB / GM, INN / GN), 256, 0, stream>>>(Og, Wout, hg, out);
}

// Round 2
// 1091.780 us; speedup vs baseline: 1.3501x; 1.3501x over previous
//
#include <hip/hip_runtime.h>
#include <cstdint>

#define TT  1024
#define BB  32
#define HH  8
#define DD  32
#define YDN 97
#define INN 256
#define BH  (BB*HH)

typedef float v2f __attribute__((ext_vector_type(2)));
typedef float v4f __attribute__((ext_vector_type(4)));

// packed fp32 FMA (v_pk_fma_f32 on CDNA)
#define PK(acc, a, b) (acc) = __builtin_elementwise_fma((a), (b), (acc))

// LDS-only barrier: drains lgkmcnt, leaves global loads/stores in flight.
__device__ __forceinline__ void bar_lds() {
    asm volatile("s_waitcnt lgkmcnt(0)\n\ts_barrier" ::: "memory");
}
__device__ __forceinline__ void wait_lds() {
    asm volatile("s_waitcnt lgkmcnt(0)" ::: "memory");
}

template<int C>
__device__ __forceinline__ float dppf(float x) {
    return __int_as_float(__builtin_amdgcn_update_dpp(
        0, __float_as_int(x), C, 0xF, 0xF, true));
}
__device__ __forceinline__ float swz16(float x) {
    return __int_as_float(__builtin_amdgcn_ds_swizzle(__float_as_int(x), 0x401F));
}
__device__ __forceinline__ float red_max32(float v) {
    v = fmaxf(v, dppf<0xB1>(v));
    v = fmaxf(v, dppf<0x4E>(v));
    v = fmaxf(v, dppf<0x141>(v));
    v = fmaxf(v, dppf<0x140>(v));
    v = fmaxf(v, swz16(v));
    return v;
}
__device__ __forceinline__ float red_sum32(float v) {
    v += dppf<0xB1>(v);
    v += dppf<0x4E>(v);
    v += dppf<0x141>(v);
    v += dppf<0x140>(v);
    v += swz16(v);
    return v;
}
__device__ __forceinline__ float rdlane(float v, int l) {
    return __int_as_float(__builtin_amdgcn_readlane(__float_as_int(v), l));
}

// exp with overflow guard (values are O(1); clamp never binds in practice)
__device__ __forceinline__ float cexp(float v) {
    return __expf(fminf(v, 60.f));
}

// 32-length dot: x,w are 16 v2f register arrays
__device__ __forceinline__ float dot32(const v2f (&x)[16], const v2f (&w)[16]) {
    v2f a0 = {0.f, 0.f}, a1 = {0.f, 0.f};
    #pragma unroll
    for (int g = 0; g < 8; g++) {
        PK(a0, x[2*g],   w[2*g]);
        PK(a1, x[2*g+1], w[2*g+1]);
    }
    v2f s = a0 + a1;
    return s.x + s.y;
}

__device__ __forceinline__ void lds_read32x2(const float* a, const float* b,
                                             v2f (&ra)[16], v2f (&rb)[16]) {
    const v4f* ap = (const v4f*)a;
    const v4f* bp = (const v4f*)b;
    #pragma unroll
    for (int j = 0; j < 8; j++) {
        v4f x = ap[j]; ra[2*j] = x.xy; ra[2*j+1] = x.zw;
        v4f y = bp[j]; rb[2*j] = y.xy; rb[2*j+1] = y.zw;
    }
}

__device__ __forceinline__ void load_x(v2f (&X)[16], const float* __restrict__ xg,
                                       int t, int bh) {
    const v4f* p = (const v4f*)(xg + ((size_t)t * BH + bh) * DD);
    #pragma unroll
    for (int g = 0; g < 8; g++) {
        v4f v = p[g];
        X[2*g] = v.xy; X[2*g+1] = v.zw;
    }
}

// ---------------------------------------------------------------------------
// Kernel 1: x = softmax(h) over last dim (rows of 32)
// ---------------------------------------------------------------------------
__global__ __launch_bounds__(256, 1) void softmax_x_kernel(
    const float* __restrict__ hg, float* __restrict__ xg)
{
    const int row  = blockIdx.x * 8 + (threadIdx.x >> 5);
    const int lane = threadIdx.x & 31;
    float v = hg[(size_t)row * DD + lane];
    float m = red_max32(v);
    float ex = __expf(v - m);
    float sm = red_sum32(ex);
    xg[(size_t)row * DD + lane] = ex * __builtin_amdgcn_rcpf(sm);
}

// ---------------------------------------------------------------------------
// Kernel 2: recurrent SRWM + fast-weight memory, wave-role pipeline.
// One block of 4 waves per (b,h). Per-iteration wave roles (NO intra-step
// cross-wave dependency; every wave consumes data produced LAST iteration):
//   wave0 (step i):   core {Wq,Wk,wb} recurrence. Own softmax (DPP), own
//                     same-wave LDS transpose round-trip. Writes u=rrq*exq -
//                     rrk*exk, normalized khat, beta0 into buf[i&1].
//   wave1 (step i-1): Wy cols 0-63; reads buf[(i&1)^1]; computes y, fq/fk
//                     exp + sums -> fbuf[i&1]; rank-1 update of Wy.
//   wave2 (step i-1): Wy cols 64-96; fv + fb -> fbuf[i&1]; rank-1 update.
//   wave3 (step i-2): fast-weight memory; reads fbuf[(i&1)^1]; writes Og.
// One bar_lds per iteration separates buffer generations.
// ---------------------------------------------------------------------------

__device__ __forceinline__ void step_A(
    const v2f (&x)[16], v2f (&sQK)[16], v2f (&sWB)[16],
    float* u_s, float* ek_s, float* b0_s, int lane)
{
    float pq = dot32(x, sQK);          // pre_q (lanes<32) / pre_k (lanes>=32)
    float pw = dot32(x, sWB);          // wb pre on lanes 0-3
    float e  = cexp(pq);
    float s  = red_sum32(e);           // per-half sums
    float so = __shfl_xor(s, 32, 64);
    float rloc = __builtin_amdgcn_rcpf(s);    // rrq on q-half, rrk on k-half
    float roth = __builtin_amdgcn_rcpf(so);   // rrk on q-half, rrq on k-half
    float eo = __shfl_xor(e, 32, 64);
    float sg = __builtin_amdgcn_rcpf(1.f + __expf(-pw));   // beta on lanes 0-3
    if (lane < 32) u_s[lane]       = rloc * e - roth * eo; // rrq*exq - rrk*exk
    else           ek_s[lane - 32] = rloc * e;             // normalized khat
    if (lane == 0) b0_s[0] = sg;                            // beta0 for Wy
    float b1 = rdlane(sg, 1), b2 = rdlane(sg, 2), b3 = rdlane(sg, 3);
    wait_lds();                       // same-wave write -> read ordering
    v2f uu[16], kk[16];
    lds_read32x2(u_s, ek_s, uu, kk);
    float du = dot32(uu, sQK);        // vq - vk for own column
    float bs = ((lane < 32) ? b1 : b2) * du;
    v2f bs2 = {bs, bs};
    #pragma unroll
    for (int j = 0; j < 16; j++) PK(sQK[j], bs2, kk[j]);
    float dw = dot32(uu, sWB);
    float bsw = b3 * dw;
    v2f bw2 = {bsw, bsw};
    #pragma unroll
    for (int j = 0; j < 16; j++) PK(sWB[j], bw2, kk[j]);
}

__device__ __forceinline__ void step_B0(
    const v2f (&x)[16], v2f (&sY)[16],
    const float* u_s, const float* ek_s, const float* b0_s,
    float* fe_s, float* rf_s, int lane)
{
    v2f uu[16], kk[16];
    lds_read32x2(u_s, ek_s, uu, kk);   // issue reads early (prev-iter data)
    float bwv = b0_s[0];
    float pre = dot32(x, sY);          // y[lane], cols 0..63
    float ef  = cexp(pre);
    float sf  = red_sum32(ef);         // fq sum (lanes<32) / fk sum (>=32)
    fe_s[lane] = ef;
    if (lane == 0)  rf_s[0] = __builtin_amdgcn_rcpf(sf);   // rrfq
    if (lane == 32) rf_s[1] = __builtin_amdgcn_rcpf(sf);   // rrfk
    float du = dot32(uu, sY);
    float bs = bwv * du;
    v2f bs2 = {bs, bs};
    #pragma unroll
    for (int j = 0; j < 16; j++) PK(sY[j], bs2, kk[j]);
}

__device__ __forceinline__ void step_B1(
    const v2f (&x)[16], v2f (&sY2)[16],
    const float* u_s, const float* ek_s, const float* b0_s,
    float* fv_s, float* fb_s, int lane)
{
    v2f uu[16], kk[16];
    lds_read32x2(u_s, ek_s, uu, kk);
    float bwv = b0_s[0];
    float pre = dot32(x, sY2);         // y[64+lane], valid lanes 0..32
    if (lane < 32)  fv_s[lane] = pre;
    if (lane == 32) fb_s[0] = __builtin_amdgcn_rcpf(1.f + __expf(-pre));
    float du = dot32(uu, sY2);
    float bs = bwv * du;
    v2f bs2 = {bs, bs};
    #pragma unroll
    for (int j = 0; j < 16; j++) PK(sY2[j], bs2, kk[j]);
}

__device__ __forceinline__ void step_C(
    v2f (&F)[16],
    const float* fe_s, const float* fv_s, const float* rf_s, const float* fb_s,
    float* __restrict__ Og, int t, int bh, int lane)
{
    if (lane < 32) {
        v2f fq[16], fk[16];
        const v4f* qp = (const v4f*)fe_s;
        #pragma unroll
        for (int j = 0; j < 8; j++) {
            v4f a = qp[j];     fq[2*j] = a.xy; fq[2*j+1] = a.zw;
            v4f b = qp[8 + j]; fk[2*j] = b.xy; fk[2*j+1] = b.zw;
        }
        float rrfq = rf_s[0], rrfk = rf_s[1];
        float fbv  = fb_s[0];
        float fvv  = fv_s[lane];
        float vp   = dot32(fk, F);                 // sum exk_d * F[d,e]
        float ds   = fbv * (fvv - vp * rrfk) * rrfk;
        v2f d2 = {ds, ds};
        v2f o0 = {0.f,0.f}, o1 = {0.f,0.f};
        #pragma unroll
        for (int j = 0; j < 8; j++) {
            PK(F[2*j],   d2, fk[2*j]);   PK(o0, fq[2*j],   F[2*j]);
            PK(F[2*j+1], d2, fk[2*j+1]); PK(o1, fq[2*j+1], F[2*j+1]);
        }
        v2f ot = o0 + o1;
        Og[((size_t)t * BH + bh) * DD + lane] = (ot.x + ot.y) * rrfq;
    }
}

__global__ __launch_bounds__(256, 1) void srwm_fwm_kernel(
    const float* __restrict__ xg,
    const float* __restrict__ Wy_g, const float* __restrict__ Wq_g,
    const float* __restrict__ Wk_g, const float* __restrict__ wb_g,
    const float* __restrict__ sWy_g, const float* __restrict__ sWq_g,
    const float* __restrict__ sWk_g, const float* __restrict__ swb_g,
    const float* __restrict__ F_g,
    float* __restrict__ Og)
{
    const int bh   = blockIdx.x;
    const int hh   = bh & 7;
    const int tid  = threadIdx.x;
    const int wv   = tid >> 6;
    const int lane = tid & 63;

    __shared__ __align__(16) float u_sh[2][32];
    __shared__ __align__(16) float ek_sh[2][32];
    __shared__ __align__(16) float b0_sh[2];
    __shared__ __align__(16) float fe_sh[2][64];
    __shared__ __align__(16) float fv_sh[2][32];
    __shared__ __align__(16) float rf_sh[2][2];
    __shared__ __align__(16) float fb_sh[2];

    v2f st[16], st2[16];   // st: main state column; st2: wb cols (wave0 only)
    v2f XA[16], XB[16];

    if (wv == 0) {
        const int l32 = lane & 31;
        const float* wp = (lane < 32) ? (Wq_g  + (size_t)hh * DD * DD + l32)
                                      : (Wk_g  + (size_t)hh * DD * DD + l32);
        const float* sp = (lane < 32) ? (sWq_g + (size_t)bh * DD * DD + l32)
                                      : (sWk_g + (size_t)bh * DD * DD + l32);
        #pragma unroll
        for (int d = 0; d < 16; d++) {
            v2f t;
            t.x = wp[(2*d)   * DD] + sp[(2*d)   * DD];
            t.y = wp[(2*d+1) * DD] + sp[(2*d+1) * DD];
            st[d] = t;
        }
        #pragma unroll
        for (int d = 0; d < 16; d++) st2[d] = (v2f){0.f, 0.f};
        if (lane < 4) {
            const float* wpb = wb_g  + (size_t)hh * DD * 4 + lane;
            const float* spb = swb_g + (size_t)bh * DD * 4 + lane;
            #pragma unroll
            for (int d = 0; d < 16; d++) {
                v2f t;
                t.x = wpb[(2*d)   * 4] + spb[(2*d)   * 4];
                t.y = wpb[(2*d+1) * 4] + spb[(2*d+1) * 4];
                st2[d] = t;
            }
        }
    } else if (wv == 1) {
        const float* wp = Wy_g  + (size_t)hh * DD * YDN + lane;
        const float* sp = sWy_g + (size_t)bh * DD * YDN + lane;
        #pragma unroll
        for (int d = 0; d < 16; d++) {
            v2f t;
            t.x = wp[(2*d)   * YDN] + sp[(2*d)   * YDN];
            t.y = wp[(2*d+1) * YDN] + sp[(2*d+1) * YDN];
            st[d] = t;
        }
    } else if (wv == 2) {
        #pragma unroll
        for (int d = 0; d < 16; d++) st[d] = (v2f){0.f, 0.f};
        if (lane <= 32) {
            const float* wp = Wy_g  + (size_t)hh * DD * YDN + 64 + lane;
            const float* sp = sWy_g + (size_t)bh * DD * YDN + 64 + lane;
            #pragma unroll
            for (int d = 0; d < 16; d++) {
                v2f t;
                t.x = wp[(2*d)   * YDN] + sp[(2*d)   * YDN];
                t.y = wp[(2*d+1) * YDN] + sp[(2*d+1) * YDN];
                st[d] = t;
            }
        }
    } else {
        if (lane < 32) {
            const float* fp = F_g + (size_t)bh * DD * DD + lane;
            #pragma unroll
            for (int d = 0; d < 16; d++) {
                v2f t;
                t.x = fp[(2*d)   * DD];
                t.y = fp[(2*d+1) * DD];
                st[d] = t;
            }
        }
    }
    if (wv < 3) {
        load_x(XA, xg, 0, bh);
        load_x(XB, xg, 1, bh);
    }
    bar_lds();

    // iteration I: wave0 does step I; wave1/2 step I-1; wave3 step I-2.
    // buffers: wave0 writes [I&1]; wave1/2 read [(I&1)^1], write f[I&1];
    // wave3 reads f[(I&1)^1].
#define ITER(I, P, XW0, XW12)                                                 \
    {                                                                         \
        if (wv == 0) {                                                        \
            if ((I) < TT) {                                                   \
                step_A(XW0, st, st2, u_sh[P], ek_sh[P], &b0_sh[P], lane);     \
                if ((I) + 2 < TT) load_x(XW0, xg, (I) + 2, bh);               \
            }                                                                 \
        } else if (wv == 1) {                                                 \
            if ((I) >= 1 && (I) <= TT) {                                      \
                step_B0(XW12, st, u_sh[(P)^1], ek_sh[(P)^1], &b0_sh[(P)^1],   \
                        fe_sh[P], rf_sh[P], lane);                            \
                if ((I) + 1 < TT) load_x(XW12, xg, (I) + 1, bh);              \
            }                                                                 \
        } else if (wv == 2) {                                                 \
            if ((I) >= 1 && (I) <= TT) {                                      \
                step_B1(XW12, st, u_sh[(P)^1], ek_sh[(P)^1], &b0_sh[(P)^1],   \
                        fv_sh[P], &fb_sh[P], lane);                           \
                if ((I) + 1 < TT) load_x(XW12, xg, (I) + 1, bh);              \
            }                                                                 \
        } else {                                                              \
            if ((I) >= 2) {                                                   \
                step_C(st, fe_sh[(P)^1], fv_sh[(P)^1], rf_sh[(P)^1],          \
                       &fb_sh[(P)^1], Og, (I) - 2, bh, lane);                 \
            }                                                                 \
        }                                                                     \
        bar_lds();                                                            \
    }

    for (int m = 0; m < (TT + 2) / 2; ++m) {
        const int i0 = 2 * m;
        ITER(i0,     0, XA, XB)
        ITER(i0 + 1, 1, XB, XA)
    }
#undef ITER
}

// ---------------------------------------------------------------------------
// Kernel 3: out = h + O @ W_out^T   (M=32768, N=K=256), fp32.
// ---------------------------------------------------------------------------
#define GM 128
#define GN 64
#define GK 16

__global__ __launch_bounds__(256, 1) void out_proj_kernel(
    const float* __restrict__ O, const float* __restrict__ W,
    const float* __restrict__ hg, float* __restrict__ outg)
{
    __shared__ float As[GK][GM + 4];
    __shared__ float Bs[GK][GN + 4];
    const int tid = threadIdx.x;
    const int tx  = tid & 15;
    const int ty  = tid >> 4;
    const int r0  = blockIdx.x * GM;
    const int c0  = blockIdx.y * GN;

    float acc[8][4];
    #pragma unroll
    for (int i = 0; i < 8; i++)
        #pragma unroll
        for (int j = 0; j < 4; j++) acc[i][j] = 0.f;

    const int am  = tid >> 1;
    const int akg = (tid & 1) * 8;
    const int bn  = tid >> 2;
    const int bkg = (tid & 3) * 4;

    for (int k0 = 0; k0 < INN; k0 += GK) {
        float4 a0 = *(const float4*)(O + (size_t)(r0 + am) * INN + k0 + akg);
        float4 a1 = *(const float4*)(O + (size_t)(r0 + am) * INN + k0 + akg + 4);
        float4 w0 = *(const float4*)(W + (size_t)(c0 + bn) * INN + k0 + bkg);
        As[akg+0][am] = a0.x; As[akg+1][am] = a0.y; As[akg+2][am] = a0.z; As[akg+3][am] = a0.w;
        As[akg+4][am] = a1.x; As[akg+5][am] = a1.y; As[akg+6][am] = a1.z; As[akg+7][am] = a1.w;
        Bs[bkg+0][bn] = w0.x; Bs[bkg+1][bn] = w0.y;
        Bs[bkg+2][bn] = w0.z; Bs[bkg+3][bn] = w0.w;
        __syncthreads();
        #pragma unroll
        for (int k = 0; k < GK; k++) {
            float4 av0 = *(const float4*)&As[k][ty * 8];
            float4 av1 = *(const float4*)&As[k][ty * 8 + 4];
            float4 bv  = *(const float4*)&Bs[k][tx * 4];
            float a[8] = {av0.x, av0.y, av0.z, av0.w, av1.x, av1.y, av1.z, av1.w};
            float bb[4] = {bv.x, bv.y, bv.z, bv.w};
            #pragma unroll
            for (int i = 0; i < 8; i++)
                #pragma unroll
                for (int j = 0; j < 4; j++) acc[i][j] += a[i] * bb[j];
        }
        __syncthreads();
    }

    #pragma unroll
    for (int i = 0; i < 8; i++) {
        size_t r = (size_t)(r0 + ty * 8 + i);
        float4 hv = *(const float4*)(hg + r * INN + c0 + tx * 4);
        float4 o;
        o.x = hv.x + acc[i][0];
        o.y = hv.y + acc[i][1];
        o.z = hv.z + acc[i][2];
        o.w = hv.w + acc[i][3];
        *(float4*)(outg + r * INN + c0 + tx * 4) = o;
    }
}

// ---------------------------------------------------------------------------
extern "C" void kernel_launch(void* const* d_in, const int* in_sizes, int n_in,
                              void* d_out, int out_size, void* d_ws, size_t ws_size,
                              hipStream_t stream)
{
    (void)in_sizes; (void)n_in; (void)out_size; (void)ws_size;

    const float* hg   = (const float*)d_in[0];
    const float* Wy   = (const float*)d_in[1];
    const float* Wq   = (const float*)d_in[2];
    const float* Wk   = (const float*)d_in[3];
    const float* wb   = (const float*)d_in[4];
    const float* Wout = (const float*)d_in[5];
    const float* sWy  = (const float*)d_in[6];
    const float* sWq  = (const float*)d_in[7];
    const float* sWk  = (const float*)d_in[8];
    const float* swb  = (const float*)d_in[9];
    const float* Fw   = (const float*)d_in[10];
    float* out = (float*)d_out;

    float* xg = (float*)d_ws;                      // (T,B,H,D) fp32
    float* Og = xg + (size_t)TT * BB * INN;        // (T,B,IN)  fp32

    softmax_x_kernel<<<TT * BB * HH / 8, 256, 0, stream>>>(hg, xg);
    srwm_fwm_kernel<<<BB * HH, 256, 0, stream>>>(xg, Wy, Wq, Wk, wb,
                                                 sWy, sWq, sWk, swb, Fw, Og);
    out_proj_kernel<<<dim3(TT * BB / GM, INN / GN), 256, 0, stream>>>(Og, Wout, hg, out);
}

// Round 4
// 803.502 us; speedup vs baseline: 1.8345x; 1.3588x over previous
//
#include <hip/hip_runtime.h>
#include <cstdint>

#define TT  1024
#define BB  32
#define HH  8
#define DD  32
#define YDN 97
#define INN 256
#define BH  (BB*HH)

typedef float v2f __attribute__((ext_vector_type(2)));
typedef float v4f __attribute__((ext_vector_type(4)));

// packed fp32 FMA (v_pk_fma_f32 on CDNA)
#define PK(acc, a, b) (acc) = __builtin_elementwise_fma((a), (b), (acc))

// LDS barrier: drains lgkmcnt, leaves global loads/stores in flight.
__device__ __forceinline__ void bar_lds() {
    asm volatile("s_waitcnt lgkmcnt(0)\n\ts_barrier" ::: "memory");
}

template<int C>
__device__ __forceinline__ float dppf(float x) {
    return __int_as_float(__builtin_amdgcn_update_dpp(
        0, __float_as_int(x), C, 0xF, 0xF, true));
}
__device__ __forceinline__ float swz16(float x) {
    return __int_as_float(__builtin_amdgcn_ds_swizzle(__float_as_int(x), 0x401F));
}
// value from lane^32 (harness-verified primitive)
__device__ __forceinline__ float xswap32(float v) {
    return __shfl_xor(v, 32, 64);
}
__device__ __forceinline__ float red_max32(float v) {
    v = fmaxf(v, dppf<0xB1>(v));
    v = fmaxf(v, dppf<0x4E>(v));
    v = fmaxf(v, dppf<0x141>(v));
    v = fmaxf(v, dppf<0x140>(v));
    v = fmaxf(v, swz16(v));
    return v;
}
__device__ __forceinline__ float red_sum32(float v) {
    v += dppf<0xB1>(v);
    v += dppf<0x4E>(v);
    v += dppf<0x141>(v);
    v += dppf<0x140>(v);
    v += swz16(v);
    return v;
}

// exp with overflow guard (values are O(1); clamp never binds in practice)
__device__ __forceinline__ float cexp(float v) {
    return __expf(fminf(v, 60.f));
}

// 32-length dot: x,w are 16 v2f register arrays
__device__ __forceinline__ float dot32(const v2f (&x)[16], const v2f (&w)[16]) {
    v2f a0 = {0.f, 0.f}, a1 = {0.f, 0.f};
    #pragma unroll
    for (int g = 0; g < 8; g++) {
        PK(a0, x[2*g],   w[2*g]);
        PK(a1, x[2*g+1], w[2*g+1]);
    }
    v2f s = a0 + a1;
    return s.x + s.y;
}

__device__ __forceinline__ void lds_read32x2(const float* a, const float* b,
                                             v2f (&ra)[16], v2f (&rb)[16]) {
    const v4f* ap = (const v4f*)a;
    const v4f* bp = (const v4f*)b;
    #pragma unroll
    for (int j = 0; j < 8; j++) {
        v4f x = ap[j]; ra[2*j] = x.xy; ra[2*j+1] = x.zw;
        v4f y = bp[j]; rb[2*j] = y.xy; rb[2*j+1] = y.zw;
    }
}

// ---------------------------------------------------------------------------
// Kernel 1: x = softmax(h) over last dim (rows of 32)
// ---------------------------------------------------------------------------
__global__ __launch_bounds__(256, 1) void softmax_x_kernel(
    const float* __restrict__ hg, float* __restrict__ xg)
{
    const int row  = blockIdx.x * 8 + (threadIdx.x >> 5);
    const int lane = threadIdx.x & 31;
    float v = hg[(size_t)row * DD + lane];
    float m = red_max32(v);
    float ex = __expf(v - m);
    float sm = red_sum32(ex);
    xg[(size_t)row * DD + lane] = ex * __builtin_amdgcn_rcpf(sm);
}

// ---------------------------------------------------------------------------
// Kernel 2: recurrent SRWM + fast-weight memory. One block (4 waves) per (b,h).
// Wave roles per step t:
//   region1: wv0: y[0..63] dots; wv1: y[64..96] + beta dots; wv2: q/k dots,
//            softmax, writes u = qhat-khat and khat (normalized);
//            wv3: PHASE_D(t-1) (fast-weight update + output, F split over
//            64 lanes: lanes<32 rows 0-15, lanes>=32 rows 16-31).
//   barrier (one per step)
//   region2: wv0/1/2 consumers: ONE dot du = u.W[:,e], rank-1 update
//            W[:,e] += beta[mat]*du*khat (+x(t+2) prefetch);
//            wv3: fq/fk exp+normalize -> fq_s/fk_s, capture fv/fb.
// ---------------------------------------------------------------------------

#define PHASE_D(TP)                                                           \
    {                                                                         \
        const v4f* q4 = (const v4f*)fq_s;                                     \
        const v4f* k4 = (const v4f*)fk_s;                                     \
        v2f fqh[8], fkh[8];                                                   \
        _Pragma("unroll")                                                     \
        for (int j = 0; j < 4; j++) {                                         \
            v4f a = q4[4*half + j];                                           \
            fqh[2*j] = a.xy; fqh[2*j+1] = a.zw;                               \
            v4f b = k4[4*half + j];                                           \
            fkh[2*j] = b.xy; fkh[2*j+1] = b.zw;                               \
        }                                                                     \
        v2f a0 = {0.f,0.f}, a1 = {0.f,0.f};                                   \
        _Pragma("unroll")                                                     \
        for (int j = 0; j < 4; j++) {                                         \
            PK(a0, fkh[2*j],   F8[2*j]);                                      \
            PK(a1, fkh[2*j+1], F8[2*j+1]);                                    \
        }                                                                     \
        v2f vt = a0 + a1;                                                     \
        float vh = vt.x + vt.y;                                               \
        float vold = vh + xswap32(vh);                                        \
        float d2s  = fb_r * (fv_r - vold);                                    \
        v2f d2 = {d2s, d2s};                                                  \
        v2f o0 = {0.f,0.f}, o1 = {0.f,0.f};                                   \
        _Pragma("unroll")                                                     \
        for (int j = 0; j < 4; j++) {                                         \
            PK(F8[2*j],   d2, fkh[2*j]);   PK(o0, fqh[2*j],   F8[2*j]);       \
            PK(F8[2*j+1], d2, fkh[2*j+1]); PK(o1, fqh[2*j+1], F8[2*j+1]);     \
        }                                                                     \
        v2f ot = o0 + o1;                                                     \
        float oh = ot.x + ot.y;                                               \
        float oo = oh + xswap32(oh);                                          \
        if (lane < DD)                                                        \
            Og[((size_t)(TP) * BH + bh) * DD + lane] = oo;                    \
    }

#define STEP(T, XC, BUF)                                                      \
  {                                                                           \
    /* ---------------- region 1 ---------------- */                          \
    if (wv == 3) {                                                            \
        if ((T) > 0) { PHASE_D((T)-1) }                                       \
    } else if (wv == 2) {                                                     \
        float pre = dot32(XC, row2);                                          \
        float ex  = cexp(pre);                                                \
        float sm  = red_sum32(ex);                                            \
        float nh  = ex * __builtin_amdgcn_rcpf(sm);                           \
        float oth = xswap32(nh);                                              \
        if (lane < DD) u_s[BUF][lane]      = nh - oth;                        \
        else           k_s[BUF][lane - DD] = nh;                              \
    } else if (mat >= 0) {                                                    \
        float pre = dot32(XC, row2);                                          \
        if (wv == 0)        y_s[BUF][lane] = pre;                             \
        else if (mat == 0)  y_s[BUF][64 + lane] = pre;                        \
        else                beta_s[BUF][lane - 33] =                          \
                 __builtin_amdgcn_rcpf(1.f + __expf(-pre));                   \
    }                                                                         \
    bar_lds();                                                                \
    /* ---------------- region 2 ---------------- */                          \
    if (wv == 3) {                                                            \
        float fpre = y_s[BUF][lane];                                          \
        float ex = cexp(fpre);                                                \
        float r  = __builtin_amdgcn_rcpf(red_sum32(ex));                      \
        float n  = ex * r;                                                    \
        if (lane < DD) fq_s[lane]      = n;                                   \
        else           fk_s[lane - DD] = n;                                   \
        fv_r = y_s[BUF][64 + (lane & 31)];                                    \
        fb_r = __builtin_amdgcn_rcpf(1.f + __expf(-y_s[BUF][96]));            \
    } else if (mat >= 0) {                                                    \
        v2f uu[16], kk[16];                                                   \
        lds_read32x2(u_s[BUF], k_s[BUF], uu, kk);                             \
        if ((T) + 2 < TT) { /* prefetch x(T+2) into XC */                     \
            const v4f* p =                                                    \
                (const v4f*)(xg + ((size_t)((T)+2)*BH + bh)*DD);              \
            _Pragma("unroll")                                                 \
            for (int g = 0; g < 8; g++) {                                     \
                v4f v = p[g];                                                 \
                XC[2*g]   = v.xy;                                             \
                XC[2*g+1] = v.zw;                                             \
            }                                                                 \
        }                                                                     \
        float du = dot32(uu, row2);                                           \
        float bs = beta_s[BUF][mat] * du;                                     \
        v2f bs2 = {bs, bs};                                                   \
        _Pragma("unroll")                                                     \
        for (int j = 0; j < 16; j++) PK(row2[j], bs2, kk[j]);                 \
    }                                                                         \
  }

__global__ __launch_bounds__(256, 1) void srwm_fwm_kernel(
    const float* __restrict__ xg,
    const float* __restrict__ Wy_g, const float* __restrict__ Wq_g,
    const float* __restrict__ Wk_g, const float* __restrict__ wb_g,
    const float* __restrict__ sWy_g, const float* __restrict__ sWq_g,
    const float* __restrict__ sWk_g, const float* __restrict__ swb_g,
    const float* __restrict__ F_g,
    float* __restrict__ Og)
{
    const int bh   = blockIdx.x;
    const int hh   = bh & 7;
    const int tid  = threadIdx.x;
    const int wv   = tid >> 6;
    const int lane = tid & 63;
    const int half = lane >> 5;
    const int l32  = lane & 31;

    __shared__ __align__(16) float y_s[2][104];
    __shared__ __align__(16) float u_s[2][DD];
    __shared__ __align__(16) float k_s[2][DD];
    __shared__ __align__(16) float beta_s[2][4];
    __shared__ __align__(16) float fq_s[DD];
    __shared__ __align__(16) float fk_s[DD];

    v2f row2[16];   // state column (waves 0-2)
    v2f F8[8];      // fast-weight half-column (wave 3)
    v2f XA[16], XB[16];
    float fv_r = 0.f, fb_r = 0.f;

    // per-thread matrix role
    int mat = -1;
    if (wv == 0) mat = 0;
    else if (wv == 1) { if (lane <= 32) mat = 0; else if (lane <= 36) mat = 3; }
    else if (wv == 2) mat = (lane < 32) ? 1 : 2;

    // ---- init state rows: row2 = (W + state)^T column ----
    if (wv < 3) {
        const float* wp = nullptr; const float* sp = nullptr; int str = 0;
        if (wv == 0) {
            wp = Wy_g  + (size_t)hh * DD * YDN + lane;
            sp = sWy_g + (size_t)bh * DD * YDN + lane;  str = YDN;
        } else if (wv == 1) {
            if (lane <= 32) {
                wp = Wy_g  + (size_t)hh * DD * YDN + 64 + lane;
                sp = sWy_g + (size_t)bh * DD * YDN + 64 + lane;  str = YDN;
            } else if (lane <= 36) {
                wp = wb_g  + (size_t)hh * DD * 4 + (lane - 33);
                sp = swb_g + (size_t)bh * DD * 4 + (lane - 33);  str = 4;
            }
        } else {
            if (lane < 32) {
                wp = Wq_g  + (size_t)hh * DD * DD + lane;
                sp = sWq_g + (size_t)bh * DD * DD + lane;
            } else {
                wp = Wk_g  + (size_t)hh * DD * DD + (lane - 32);
                sp = sWk_g + (size_t)bh * DD * DD + (lane - 32);
            }
            str = DD;
        }
        #pragma unroll
        for (int d = 0; d < 16; d++) {
            v2f t = {0.f, 0.f};
            if (wp) {
                t.x = wp[(2*d)   * str] + sp[(2*d)   * str];
                t.y = wp[(2*d+1) * str] + sp[(2*d+1) * str];
            }
            row2[d] = t;
        }
        // x(0), x(1)
        const v4f* p0 = (const v4f*)(xg + (size_t)bh * DD);
        const v4f* p1 = (const v4f*)(xg + ((size_t)BH + bh) * DD);
        #pragma unroll
        for (int g = 0; g < 8; g++) {
            v4f a = p0[g], b = p1[g];
            XA[2*g] = a.xy; XA[2*g+1] = a.zw;
            XB[2*g] = b.xy; XB[2*g+1] = b.zw;
        }
    } else {
        // F split: lane (e=l32, half h) holds F[16h .. 16h+15, e]
        const float* fp = F_g + (size_t)bh * DD * DD + (size_t)(16*half) * DD + l32;
        #pragma unroll
        for (int j = 0; j < 8; j++) {
            v2f t;
            t.x = fp[(2*j)   * DD];
            t.y = fp[(2*j+1) * DD];
            F8[j] = t;
        }
    }

    for (int t = 0; t < TT; t += 2) {
        STEP(t,     XA, 0)
        STEP(t + 1, XB, 1)
    }
    // drain the pipeline: Phase D for t = TT-1
    if (wv == 3) { PHASE_D(TT - 1) }
}

// ---------------------------------------------------------------------------
// Kernel 3: out = h + O @ W_out^T   (M=32768, N=K=256), fp32.
// 128x128 tile, 8x8 microtile: 64 FMA per 4 LDS b128 reads.
// ---------------------------------------------------------------------------
#define GM 128
#define GN 128
#define GK 16

__global__ __launch_bounds__(256, 1) void out_proj_kernel(
    const float* __restrict__ O, const float* __restrict__ W,
    const float* __restrict__ hg, float* __restrict__ outg)
{
    __shared__ float As[GK][GM + 4];
    __shared__ float Bs[GK][GN + 4];
    const int tid = threadIdx.x;
    const int tx  = tid & 15;
    const int ty  = tid >> 4;
    const int r0  = blockIdx.x * GM;
    const int c0  = blockIdx.y * GN;

    float acc[8][8];
    #pragma unroll
    for (int i = 0; i < 8; i++)
        #pragma unroll
        for (int j = 0; j < 8; j++) acc[i][j] = 0.f;

    const int am = tid >> 1;
    const int ak = (tid & 1) * 8;

    for (int k0 = 0; k0 < INN; k0 += GK) {
        float4 a0 = *(const float4*)(O + (size_t)(r0 + am) * INN + k0 + ak);
        float4 a1 = *(const float4*)(O + (size_t)(r0 + am) * INN + k0 + ak + 4);
        float4 b0 = *(const float4*)(W + (size_t)(c0 + am) * INN + k0 + ak);
        float4 b1 = *(const float4*)(W + (size_t)(c0 + am) * INN + k0 + ak + 4);
        As[ak+0][am] = a0.x; As[ak+1][am] = a0.y; As[ak+2][am] = a0.z; As[ak+3][am] = a0.w;
        As[ak+4][am] = a1.x; As[ak+5][am] = a1.y; As[ak+6][am] = a1.z; As[ak+7][am] = a1.w;
        Bs[ak+0][am] = b0.x; Bs[ak+1][am] = b0.y; Bs[ak+2][am] = b0.z; Bs[ak+3][am] = b0.w;
        Bs[ak+4][am] = b1.x; Bs[ak+5][am] = b1.y; Bs[ak+6][am] = b1.z; Bs[ak+7][am] = b1.w;
        __syncthreads();
        #pragma unroll
        for (int k = 0; k < GK; k++) {
            float4 av0 = *(const float4*)&As[k][ty * 8];
            float4 av1 = *(const float4*)&As[k][ty * 8 + 4];
            float4 bv0 = *(const float4*)&Bs[k][tx * 8];
            float4 bv1 = *(const float4*)&Bs[k][tx * 8 + 4];
            float a[8] = {av0.x, av0.y, av0.z, av0.w, av1.x, av1.y, av1.z, av1.w};
            float bb[8] = {bv0.x, bv0.y, bv0.z, bv0.w, bv1.x, bv1.y, bv1.z, bv1.w};
            #pragma unroll
            for (int i = 0; i < 8; i++)
                #pragma unroll
                for (int j = 0; j < 8; j++) acc[i][j] += a[i] * bb[j];
        }
        __syncthreads();
    }

    #pragma unroll
    for (int i = 0; i < 8; i++) {
        size_t r = (size_t)(r0 + ty * 8 + i);
        float4 h0 = *(const float4*)(hg + r * INN + c0 + tx * 8);
        float4 h1 = *(const float4*)(hg + r * INN + c0 + tx * 8 + 4);
        float4 o0, o1;
        o0.x = h0.x + acc[i][0]; o0.y = h0.y + acc[i][1];
        o0.z = h0.z + acc[i][2]; o0.w = h0.w + acc[i][3];
        o1.x = h1.x + acc[i][4]; o1.y = h1.y + acc[i][5];
        o1.z = h1.z + acc[i][6]; o1.w = h1.w + acc[i][7];
        *(float4*)(outg + r * INN + c0 + tx * 8)     = o0;
        *(float4*)(outg + r * INN + c0 + tx * 8 + 4) = o1;
    }
}

// ---------------------------------------------------------------------------
extern "C" void kernel_launch(void* const* d_in, const int* in_sizes, int n_in,
                              void* d_out, int out_size, void* d_ws, size_t ws_size,
                              hipStream_t stream)
{
    (void)in_sizes; (void)n_in; (void)out_size; (void)ws_size;

    const float* hg   = (const float*)d_in[0];
    const float* Wy   = (const float*)d_in[1];
    const float* Wq   = (const float*)d_in[2];
    const float* Wk   = (const float*)d_in[3];
    const float* wb   = (const float*)d_in[4];
    const float* Wout = (const float*)d_in[5];
    const float* sWy  = (const float*)d_in[6];
    const float* sWq  = (const float*)d_in[7];
    const float* sWk  = (const float*)d_in[8];
    const float* swb  = (const float*)d_in[9];
    const float* Fw   = (const float*)d_in[10];
    float* out = (float*)d_out;

    float* xg = (float*)d_ws;                      // (T,B,H,D) fp32
    float* Og = xg + (size_t)TT * BB * INN;        // (T,B,IN)  fp32

    softmax_x_kernel<<<TT * BB * HH / 8, 256, 0, stream>>>(hg, xg);
    srwm_fwm_kernel<<<BB * HH, 256, 0, stream>>>(xg, Wy, Wq, Wk, wb,
                                                 sWy, sWq, sWk, swb, Fw, Og);
    out_proj_kernel<<<dim3(TT * BB / GM, INN / GN), 256, 0, stream>>>(Og, Wout, hg, out);
}

// Round 5
// 652.435 us; speedup vs baseline: 2.2593x; 1.2315x over previous
//
#include <hip/hip_runtime.h>
#include <cstdint>

#define TT  1024
#define BB  32
#define HH  8
#define DD  32
#define YDN 97
#define INN 256
#define BH  (BB*HH)

typedef float v2f __attribute__((ext_vector_type(2)));
typedef float v4f __attribute__((ext_vector_type(4)));

// packed fp32 FMA (v_pk_fma_f32 on CDNA)
#define PK(acc, a, b) (acc) = __builtin_elementwise_fma((a), (b), (acc))

// LDS barrier: drains lgkmcnt, leaves global loads/stores in flight.
__device__ __forceinline__ void bar_lds() {
    asm volatile("s_waitcnt lgkmcnt(0)\n\ts_barrier" ::: "memory");
}
__device__ __forceinline__ void wait_lds() {
    asm volatile("s_waitcnt lgkmcnt(0)" ::: "memory");
}

template<int C>
__device__ __forceinline__ float dppf(float x) {
    return __int_as_float(__builtin_amdgcn_update_dpp(
        0, __float_as_int(x), C, 0xF, 0xF, true));
}
__device__ __forceinline__ float swz16(float x) {
    return __int_as_float(__builtin_amdgcn_ds_swizzle(__float_as_int(x), 0x401F));
}
// value from lane^32 (harness-verified primitive)
__device__ __forceinline__ float xswap32(float v) {
    return __shfl_xor(v, 32, 64);
}
__device__ __forceinline__ float red_max32(float v) {
    v = fmaxf(v, dppf<0xB1>(v));
    v = fmaxf(v, dppf<0x4E>(v));
    v = fmaxf(v, dppf<0x141>(v));
    v = fmaxf(v, dppf<0x140>(v));
    v = fmaxf(v, swz16(v));
    return v;
}
__device__ __forceinline__ float red_sum32(float v) {
    v += dppf<0xB1>(v);
    v += dppf<0x4E>(v);
    v += dppf<0x141>(v);
    v += dppf<0x140>(v);
    v += swz16(v);
    return v;
}

// exp with overflow guard (values are O(1); clamp never binds in practice)
__device__ __forceinline__ float cexp(float v) {
    return __expf(fminf(v, 60.f));
}

// 32-length dot: x,w are 16 v2f register arrays
__device__ __forceinline__ float dot32(const v2f (&x)[16], const v2f (&w)[16]) {
    v2f a0 = {0.f, 0.f}, a1 = {0.f, 0.f};
    #pragma unroll
    for (int g = 0; g < 8; g++) {
        PK(a0, x[2*g],   w[2*g]);
        PK(a1, x[2*g+1], w[2*g+1]);
    }
    v2f s = a0 + a1;
    return s.x + s.y;
}

__device__ __forceinline__ void lds_read32x2(const float* a, const float* b,
                                             v2f (&ra)[16], v2f (&rb)[16]) {
    const v4f* ap = (const v4f*)a;
    const v4f* bp = (const v4f*)b;
    #pragma unroll
    for (int j = 0; j < 8; j++) {
        v4f x = ap[j]; ra[2*j] = x.xy; ra[2*j+1] = x.zw;
        v4f y = bp[j]; rb[2*j] = y.xy; rb[2*j+1] = y.zw;
    }
}

// consumer rank-1 update: row2 += beta * (u . row2) * khat
__device__ __forceinline__ void upd_row(v2f (&row2)[16], const float* u_p,
                                        const float* k_p, float beta) {
    v2f uu0[16], kk0[16];
    lds_read32x2(u_p, k_p, uu0, kk0);
    float du = dot32(uu0, row2);
    float bs = beta * du;
    v2f bs2 = {bs, bs};
    #pragma unroll
    for (int j = 0; j < 16; j++) PK(row2[j], bs2, kk0[j]);
}

// ---------------------------------------------------------------------------
// Kernel 1: x = softmax(h) over last dim (rows of 32)
// ---------------------------------------------------------------------------
__global__ __launch_bounds__(256, 1) void softmax_x_kernel(
    const float* __restrict__ hg, float* __restrict__ xg)
{
    const int row  = blockIdx.x * 8 + (threadIdx.x >> 5);
    const int lane = threadIdx.x & 31;
    float v = hg[(size_t)row * DD + lane];
    float m = red_max32(v);
    float ex = __expf(v - m);
    float sm = red_sum32(ex);
    xg[(size_t)row * DD + lane] = ex * __builtin_amdgcn_rcpf(sm);
}

// ---------------------------------------------------------------------------
// Kernel 2: recurrent SRWM + fast-weight memory. One block (4 waves) per
// (b,h). SINGLE-REGION lagged schedule: one barrier per step, each wave does
// its whole step-job in one region consuming data produced LAST iteration.
//   wave0: Wy cols 0-63:  update(t-1) -> y dots(t) -> write raw exp(y) (fq|fk)
//   wave1: Wy cols 64-96 + wb: update(t-1) -> dots(t) -> write raw fv/y96,
//          sigmoid betas
//   wave2: Wq|Wk: update(t-1) w/ carried uu/kk regs -> dots(t) -> softmax ->
//          write u(t)=qhat-khat, khat(t) -> same-wave readback into uu/kk
//   wave3: PHASE_D(t-1): fast-weight update + output. Normalization of fq/fk
//          folded as scalars (deferred-norm), sums computed in-lane.
// ---------------------------------------------------------------------------

#define PHASE_D(TP, P)                                                        \
    {                                                                         \
        const v4f* e4 = (const v4f*)exf_s[P];                                 \
        v2f fqh[8], fkh[8];                                                   \
        _Pragma("unroll")                                                     \
        for (int j = 0; j < 4; j++) {                                         \
            v4f a = e4[4*half + j];                                           \
            fqh[2*j] = a.xy; fqh[2*j+1] = a.zw;                               \
            v4f b = e4[8 + 4*half + j];                                       \
            fkh[2*j] = b.xy; fkh[2*j+1] = b.zw;                               \
        }                                                                     \
        float fvv = yv_s[P][l32];                                            \
        float fbp = yv_s[P][32];                                             \
        /* own-half sums of raw exps (in-lane) */                             \
        v2f sq2 = {0.f,0.f}, sk2 = {0.f,0.f};                                 \
        _Pragma("unroll")                                                     \
        for (int j = 0; j < 8; j++) { sq2 += fqh[j]; sk2 += fkh[j]; }         \
        float sq = sq2.x + sq2.y, sk = sk2.x + sk2.y;                         \
        /* partial dot over own 16 rows: sum fk_d * F[d,e] */                 \
        v2f a0 = {0.f,0.f}, a1 = {0.f,0.f};                                   \
        _Pragma("unroll")                                                     \
        for (int j = 0; j < 4; j++) {                                         \
            PK(a0, fkh[2*j],   F8[2*j]);                                      \
            PK(a1, fkh[2*j+1], F8[2*j+1]);                                    \
        }                                                                     \
        v2f vt = a0 + a1;                                                     \
        float vh = vt.x + vt.y;                                               \
        float voldr = vh + xswap32(vh);                                       \
        float sqt = sq + xswap32(sq);                                         \
        float skt = sk + xswap32(sk);                                         \
        float rrfq = __builtin_amdgcn_rcpf(sqt);                              \
        float rrfk = __builtin_amdgcn_rcpf(skt);                              \
        float fbv  = __builtin_amdgcn_rcpf(1.f + __expf(-fbp));               \
        float sup  = fbv * (fvv - rrfk * voldr) * rrfk;                       \
        v2f d2 = {sup, sup};                                                  \
        v2f o0 = {0.f,0.f}, o1 = {0.f,0.f};                                   \
        _Pragma("unroll")                                                     \
        for (int j = 0; j < 4; j++) {                                         \
            PK(F8[2*j],   d2, fkh[2*j]);   PK(o0, fqh[2*j],   F8[2*j]);       \
            PK(F8[2*j+1], d2, fkh[2*j+1]); PK(o1, fqh[2*j+1], F8[2*j+1]);     \
        }                                                                     \
        v2f ot = o0 + o1;                                                     \
        float oh = ot.x + ot.y;                                               \
        float oo = (oh + xswap32(oh)) * rrfq;                                 \
        if (lane < DD)                                                        \
            Og[((size_t)(TP) * BH + bh) * DD + lane] = oo;                    \
    }

#define PREFETCH(T, XC)                                                       \
    if ((T) + 2 < TT) {                                                       \
        const v4f* p = (const v4f*)(xg + ((size_t)((T)+2)*BH + bh)*DD);       \
        _Pragma("unroll")                                                     \
        for (int g = 0; g < 8; g++) {                                         \
            v4f v = p[g];                                                     \
            XC[2*g]   = v.xy;                                                 \
            XC[2*g+1] = v.zw;                                                 \
        }                                                                     \
    }

#define STEP_I(T, XC, P, PM)                                                  \
  {                                                                           \
    if (wv == 2) {                                                            \
        if ((T) > 0) {                                                        \
            float bb = (lane < 32) ? beta_s[PM][1] : beta_s[PM][2];           \
            float du = dot32(uu, row2);                                       \
            float bs = bb * du;                                               \
            v2f bs2 = {bs, bs};                                               \
            _Pragma("unroll")                                                 \
            for (int j = 0; j < 16; j++) PK(row2[j], bs2, kk[j]);             \
        }                                                                     \
        float pre = dot32(XC, row2);                                          \
        float ex  = cexp(pre);                                                \
        float sm  = red_sum32(ex);                                            \
        float nh  = ex * __builtin_amdgcn_rcpf(sm);                           \
        float oth = xswap32(nh);                                              \
        if (lane < DD) u_s[P][lane]      = nh - oth;                          \
        else           k_s[P][lane - DD] = nh;                                \
        wait_lds();   /* writes done; readback (wait folded into bar) */      \
        lds_read32x2(u_s[P], k_s[P], uu, kk);                                 \
        PREFETCH(T, XC)                                                       \
    } else if (wv == 0) {                                                     \
        if ((T) > 0) upd_row(row2, u_s[PM], k_s[PM], beta_s[PM][0]);          \
        float pre = dot32(XC, row2);                                          \
        exf_s[P][lane] = cexp(pre);                                           \
        PREFETCH(T, XC)                                                       \
    } else if (wv == 1) {                                                     \
        if ((T) > 0) {                                                        \
            float bb = (lane <= 32) ? beta_s[PM][0] : beta_s[PM][3];          \
            upd_row(row2, u_s[PM], k_s[PM], bb);                              \
        }                                                                     \
        float pre = dot32(XC, row2);                                          \
        if (lane <= DD)      yv_s[P][lane] = pre;                             \
        else if (lane <= 36) beta_s[P][lane - 33] =                           \
                 __builtin_amdgcn_rcpf(1.f + __expf(-pre));                   \
        PREFETCH(T, XC)                                                       \
    } else {                                                                  \
        if ((T) > 0) { PHASE_D((T)-1, PM) }                                   \
    }                                                                         \
    bar_lds();                                                                \
  }

__global__ __launch_bounds__(256, 1) void srwm_fwm_kernel(
    const float* __restrict__ xg,
    const float* __restrict__ Wy_g, const float* __restrict__ Wq_g,
    const float* __restrict__ Wk_g, const float* __restrict__ wb_g,
    const float* __restrict__ sWy_g, const float* __restrict__ sWq_g,
    const float* __restrict__ sWk_g, const float* __restrict__ swb_g,
    const float* __restrict__ F_g,
    float* __restrict__ Og)
{
    const int bh   = blockIdx.x;
    const int hh   = bh & 7;
    const int tid  = threadIdx.x;
    const int wv   = tid >> 6;
    const int lane = tid & 63;
    const int half = lane >> 5;
    const int l32  = lane & 31;

    __shared__ __align__(16) float u_s[2][DD];
    __shared__ __align__(16) float k_s[2][DD];
    __shared__ __align__(16) float exf_s[2][64];
    __shared__ __align__(16) float yv_s[2][36];
    __shared__ __align__(16) float beta_s[2][4];

    v2f row2[16];         // state column (waves 0-2)
    v2f F8[8];            // fast-weight half-column (wave 3)
    v2f uu[16], kk[16];   // wave2 carried u/khat vectors
    v2f XA[16], XB[16];

    // ---- init state rows: row2 = (W + state)^T column ----
    if (wv < 3) {
        const float* wp = nullptr; const float* sp = nullptr; int str = 0;
        if (wv == 0) {
            wp = Wy_g  + (size_t)hh * DD * YDN + lane;
            sp = sWy_g + (size_t)bh * DD * YDN + lane;  str = YDN;
        } else if (wv == 1) {
            if (lane <= 32) {
                wp = Wy_g  + (size_t)hh * DD * YDN + 64 + lane;
                sp = sWy_g + (size_t)bh * DD * YDN + 64 + lane;  str = YDN;
            } else if (lane <= 36) {
                wp = wb_g  + (size_t)hh * DD * 4 + (lane - 33);
                sp = swb_g + (size_t)bh * DD * 4 + (lane - 33);  str = 4;
            }
        } else {
            if (lane < 32) {
                wp = Wq_g  + (size_t)hh * DD * DD + lane;
                sp = sWq_g + (size_t)bh * DD * DD + lane;
            } else {
                wp = Wk_g  + (size_t)hh * DD * DD + (lane - 32);
                sp = sWk_g + (size_t)bh * DD * DD + (lane - 32);
            }
            str = DD;
        }
        #pragma unroll
        for (int d = 0; d < 16; d++) {
            v2f t = {0.f, 0.f};
            if (wp) {
                t.x = wp[(2*d)   * str] + sp[(2*d)   * str];
                t.y = wp[(2*d+1) * str] + sp[(2*d+1) * str];
            }
            row2[d] = t;
        }
        // x(0), x(1)
        const v4f* p0 = (const v4f*)(xg + (size_t)bh * DD);
        const v4f* p1 = (const v4f*)(xg + ((size_t)BH + bh) * DD);
        #pragma unroll
        for (int g = 0; g < 8; g++) {
            v4f a = p0[g], b = p1[g];
            XA[2*g] = a.xy; XA[2*g+1] = a.zw;
            XB[2*g] = b.xy; XB[2*g+1] = b.zw;
        }
    } else {
        // F split: lane (e=l32, half h) holds F[16h .. 16h+15, e]
        const float* fp = F_g + (size_t)bh * DD * DD + (size_t)(16*half) * DD + l32;
        #pragma unroll
        for (int j = 0; j < 8; j++) {
            v2f t;
            t.x = fp[(2*j)   * DD];
            t.y = fp[(2*j+1) * DD];
            F8[j] = t;
        }
    }

    for (int t = 0; t < TT; t += 2) {
        STEP_I(t,     XA, 0, 1)
        STEP_I(t + 1, XB, 1, 0)
    }
    // drain: FWM for t = TT-1 (buffers parity (TT-1)&1 = 1)
    if (wv == 3) { PHASE_D(TT - 1, 1) }
}

// ---------------------------------------------------------------------------
// Kernel 3: out = h + O @ W_out^T   (M=32768, N=K=256), fp32.
// 128x128 tile, 8x8 microtile: 64 FMA per 4 LDS b128 reads.
// ---------------------------------------------------------------------------
#define GM 128
#define GN 128
#define GK 16

__global__ __launch_bounds__(256, 1) void out_proj_kernel(
    const float* __restrict__ O, const float* __restrict__ W,
    const float* __restrict__ hg, float* __restrict__ outg)
{
    __shared__ float As[GK][GM + 4];
    __shared__ float Bs[GK][GN + 4];
    const int tid = threadIdx.x;
    const int tx  = tid & 15;
    const int ty  = tid >> 4;
    const int r0  = blockIdx.x * GM;
    const int c0  = blockIdx.y * GN;

    float acc[8][8];
    #pragma unroll
    for (int i = 0; i < 8; i++)
        #pragma unroll
        for (int j = 0; j < 8; j++) acc[i][j] = 0.f;

    const int am = tid >> 1;
    const int ak = (tid & 1) * 8;

    for (int k0 = 0; k0 < INN; k0 += GK) {
        float4 a0 = *(const float4*)(O + (size_t)(r0 + am) * INN + k0 + ak);
        float4 a1 = *(const float4*)(O + (size_t)(r0 + am) * INN + k0 + ak + 4);
        float4 b0 = *(const float4*)(W + (size_t)(c0 + am) * INN + k0 + ak);
        float4 b1 = *(const float4*)(W + (size_t)(c0 + am) * INN + k0 + ak + 4);
        As[ak+0][am] = a0.x; As[ak+1][am] = a0.y; As[ak+2][am] = a0.z; As[ak+3][am] = a0.w;
        As[ak+4][am] = a1.x; As[ak+5][am] = a1.y; As[ak+6][am] = a1.z; As[ak+7][am] = a1.w;
        Bs[ak+0][am] = b0.x; Bs[ak+1][am] = b0.y; Bs[ak+2][am] = b0.z; Bs[ak+3][am] = b0.w;
        Bs[ak+4][am] = b1.x; Bs[ak+5][am] = b1.y; Bs[ak+6][am] = b1.z; Bs[ak+7][am] = b1.w;
        __syncthreads();
        #pragma unroll
        for (int k = 0; k < GK; k++) {
            float4 av0 = *(const float4*)&As[k][ty * 8];
            float4 av1 = *(const float4*)&As[k][ty * 8 + 4];
            float4 bv0 = *(const float4*)&Bs[k][tx * 8];
            float4 bv1 = *(const float4*)&Bs[k][tx * 8 + 4];
            float a[8] = {av0.x, av0.y, av0.z, av0.w, av1.x, av1.y, av1.z, av1.w};
            float bb[8] = {bv0.x, bv0.y, bv0.z, bv0.w, bv1.x, bv1.y, bv1.z, bv1.w};
            #pragma unroll
            for (int i = 0; i < 8; i++)
                #pragma unroll
                for (int j = 0; j < 8; j++) acc[i][j] += a[i] * bb[j];
        }
        __syncthreads();
    }

    #pragma unroll
    for (int i = 0; i < 8; i++) {
        size_t r = (size_t)(r0 + ty * 8 + i);
        float4 h0 = *(const float4*)(hg + r * INN + c0 + tx * 8);
        float4 h1 = *(const float4*)(hg + r * INN + c0 + tx * 8 + 4);
        float4 o0, o1;
        o0.x = h0.x + acc[i][0]; o0.y = h0.y + acc[i][1];
        o0.z = h0.z + acc[i][2]; o0.w = h0.w + acc[i][3];
        o1.x = h1.x + acc[i][4]; o1.y = h1.y + acc[i][5];
        o1.z = h1.z + acc[i][6]; o1.w = h1.w + acc[i][7];
        *(float4*)(outg + r * INN + c0 + tx * 8)     = o0;
        *(float4*)(outg + r * INN + c0 + tx * 8 + 4) = o1;
    }
}

// ---------------------------------------------------------------------------
extern "C" void kernel_launch(void* const* d_in, const int* in_sizes, int n_in,
                              void* d_out, int out_size, void* d_ws, size_t ws_size,
                              hipStream_t stream)
{
    (void)in_sizes; (void)n_in; (void)out_size; (void)ws_size;

    const float* hg   = (const float*)d_in[0];
    const float* Wy   = (const float*)d_in[1];
    const float* Wq   = (const float*)d_in[2];
    const float* Wk   = (const float*)d_in[3];
    const float* wb   = (const float*)d_in[4];
    const float* Wout = (const float*)d_in[5];
    const float* sWy  = (const float*)d_in[6];
    const float* sWq  = (const float*)d_in[7];
    const float* sWk  = (const float*)d_in[8];
    const float* swb  = (const float*)d_in[9];
    const float* Fw   = (const float*)d_in[10];
    float* out = (float*)d_out;

    float* xg = (float*)d_ws;                      // (T,B,H,D) fp32
    float* Og = xg + (size_t)TT * BB * INN;        // (T,B,IN)  fp32

    softmax_x_kernel<<<TT * BB * HH / 8, 256, 0, stream>>>(hg, xg);
    srwm_fwm_kernel<<<BB * HH, 256, 0, stream>>>(xg, Wy, Wq, Wk, wb,
                                                 sWy, sWq, sWk, swb, Fw, Og);
    out_proj_kernel<<<dim3(TT * BB / GM, INN / GN), 256, 0, stream>>>(Og, Wout, hg, out);
}